// Round 2
// baseline (2090.470 us; speedup 1.0000x reference)
//
#include <hip/hip_runtime.h>
#include <hip/hip_bf16.h>
#include <math.h>

// Memory module: E=768, S=128, T=3, B=64, L=512. fp32 in/out.
// bf16 MFMA GEMMs (fp32 accum); LN/softmax/GRU combine in fp32.
// Workspace plan: 226,230,272 bytes with static region reuse (see offsets below).

typedef __attribute__((ext_vector_type(4))) float f32x4;
typedef __attribute__((ext_vector_type(8))) short short8;
typedef __attribute__((ext_vector_type(4))) unsigned short us4;

__device__ __forceinline__ unsigned short f2bf(float x) {
  union { float f; unsigned u; } v; v.f = x;
  unsigned r = v.u + 0x7fffu + ((v.u >> 16) & 1u);  // RNE
  return (unsigned short)(r >> 16);
}

__device__ __forceinline__ void g2l16(const void* g, void* l) {
  __builtin_amdgcn_global_load_lds(
      (const __attribute__((address_space(1))) unsigned int*)g,
      (__attribute__((address_space(3))) unsigned int*)l, 16, 0, 0);
}

__device__ __forceinline__ float wsum(float v) {
#pragma unroll
  for (int o = 32; o > 0; o >>= 1) v += __shfl_xor(v, o, 64);
  return v;
}
__device__ __forceinline__ float wmax(float v) {
#pragma unroll
  for (int o = 32; o > 0; o >>= 1) v = fmaxf(v, __shfl_xor(v, o, 64));
  return v;
}

// C = alpha*(A @ B^T) + bias. A[M,K] bf16 lda=K, B[N,K] bf16 ldb=K, C[M,N] ldc=N.
// Batched over blockIdx.z (strides sA/sB/sC elements). OMODE 0: fp32 out, 1: bf16.
// Requires per-batch M%128==0, N%128==0, K%32==0.
template<int OMODE, bool BIAS>
__global__ __launch_bounds__(256) void gemm_nt(
    const unsigned short* __restrict__ Ag, const unsigned short* __restrict__ Bg,
    const float* __restrict__ bias, void* __restrict__ Cg,
    int M, int N, int K, long long sA, long long sB, long long sC, float alpha)
{
  __shared__ __align__(16) unsigned short As[128 * 32];
  __shared__ __align__(16) unsigned short Bs[128 * 32];

  const int tid  = threadIdx.x;
  const int lane = tid & 63;
  const int wv   = tid >> 6;           // 0..3
  const int wr   = wv >> 1, wc = wv & 1;
  const int tn   = blockIdx.x, tm = blockIdx.y;
  const long long bz = blockIdx.z;

  const unsigned short* A = Ag + bz * sA + (size_t)tm * 128 * K;
  const unsigned short* B = Bg + bz * sB + (size_t)tn * 128 * K;

  const int srow = wv * 16 + (lane >> 2);   // staging row (+ i*64)
  const int kby  = (lane & 3) * 16;         // byte offset within 64B k-row

  f32x4 acc[4][4];
#pragma unroll
  for (int a = 0; a < 4; ++a)
#pragma unroll
    for (int b = 0; b < 4; ++b) acc[a][b] = (f32x4)(0.f);

  const int mrow = wr * 64 + (lane & 15);
  const int nrow = wc * 64 + (lane & 15);
  const int koff = (lane >> 4) * 8;

  for (int kt = 0; kt < K; kt += 32) {
#pragma unroll
    for (int i = 0; i < 2; ++i) {
      g2l16((const char*)(A + (size_t)(i * 64 + srow) * K + kt) + kby,
            (char*)As + i * 4096 + wv * 1024);
      g2l16((const char*)(B + (size_t)(i * 64 + srow) * K + kt) + kby,
            (char*)Bs + i * 4096 + wv * 1024);
    }
    __syncthreads();
    short8 af[4], bf[4];
#pragma unroll
    for (int a = 0; a < 4; ++a) af[a] = *(const short8*)&As[(mrow + a * 16) * 32 + koff];
#pragma unroll
    for (int b = 0; b < 4; ++b) bf[b] = *(const short8*)&Bs[(nrow + b * 16) * 32 + koff];
#pragma unroll
    for (int a = 0; a < 4; ++a)
#pragma unroll
      for (int b = 0; b < 4; ++b)
        acc[a][b] = __builtin_amdgcn_mfma_f32_16x16x32_bf16(af[a], bf[b], acc[a][b], 0, 0, 0);
    __syncthreads();
  }

  const size_t cb = (size_t)bz * sC;
#pragma unroll
  for (int a = 0; a < 4; ++a) {
    const int row0 = tm * 128 + wr * 64 + a * 16 + (lane >> 4) * 4;
#pragma unroll
    for (int b = 0; b < 4; ++b) {
      const int col = tn * 128 + wc * 64 + b * 16 + (lane & 15);
      float bv = 0.f;
      if (BIAS) bv = bias[col];
#pragma unroll
      for (int r = 0; r < 4; ++r) {
        float v = acc[a][b][r] * alpha + bv;
        if constexpr (OMODE == 0)
          ((float*)Cg)[cb + (size_t)(row0 + r) * N + col] = v;
        else
          ((unsigned short*)Cg)[cb + (size_t)(row0 + r) * N + col] = f2bf(v);
      }
    }
  }
}

// LayerNorm rows of 768; writes fp32 + bf16. One wave per row, 4 rows/block.
__global__ __launch_bounds__(256) void ln_kernel(
    const float* __restrict__ x, float* __restrict__ y, unsigned short* __restrict__ yb,
    const float* __restrict__ g, const float* __restrict__ b)
{
  const int row  = blockIdx.x * 4 + (threadIdx.x >> 6);
  const int lane = threadIdx.x & 63;
  const float* xr = x + (size_t)row * 768;
  float v[12];
  float s = 0.f;
#pragma unroll
  for (int j = 0; j < 12; ++j) { v[j] = xr[lane + 64 * j]; s += v[j]; }
  s = wsum(s);
  const float mu = s * (1.f / 768.f);
  float q = 0.f;
#pragma unroll
  for (int j = 0; j < 12; ++j) { const float d = v[j] - mu; q += d * d; }
  q = wsum(q);
  const float rstd = rsqrtf(q * (1.f / 768.f) + 1e-5f);
  float* yr = y + (size_t)row * 768;
  unsigned short* ybr = yb + (size_t)row * 768;
#pragma unroll
  for (int j = 0; j < 12; ++j) {
    const int c = lane + 64 * j;
    const float o = (v[j] - mu) * rstd * g[c] + b[c];
    yr[c] = o;
    ybr[c] = f2bf(o);
  }
}

template<int LR>
__global__ __launch_bounds__(256) void softmax_kernel(
    const float* __restrict__ sc, unsigned short* __restrict__ p)
{
  const int row  = blockIdx.x * 4 + (threadIdx.x >> 6);
  const int lane = threadIdx.x & 63;
  constexpr int PER = LR / 64;
  const float* sr = sc + (size_t)row * LR;
  float v[PER];
  float m = -1e30f;
#pragma unroll
  for (int j = 0; j < PER; ++j) { v[j] = sr[lane + 64 * j]; m = fmaxf(m, v[j]); }
  m = wmax(m);
  float s = 0.f;
#pragma unroll
  for (int j = 0; j < PER; ++j) { v[j] = __expf(v[j] - m); s += v[j]; }
  s = wsum(s);
  const float inv = 1.f / s;
  unsigned short* pr = p + (size_t)row * LR;
#pragma unroll
  for (int j = 0; j < PER; ++j) pr[lane + 64 * j] = f2bf(v[j] * inv);
}

// GRU combine: gi/gh fp32 [rows,2304] (r,z,n), h fp32 [rows,768] -> out fp32.
__global__ __launch_bounds__(256) void gru_combine(
    const float* __restrict__ gi, const float* __restrict__ gh,
    const float* __restrict__ h, float* __restrict__ out)
{
  const size_t row = blockIdx.x;
#pragma unroll
  for (int k = 0; k < 3; ++k) {
    const int c = threadIdx.x + k * 256;
    const float ir  = gi[row * 2304 + c];
    const float iz  = gi[row * 2304 + 768 + c];
    const float in_ = gi[row * 2304 + 1536 + c];
    const float hr  = gh[row * 2304 + c];
    const float hz  = gh[row * 2304 + 768 + c];
    const float hn  = gh[row * 2304 + 1536 + c];
    const float r  = 1.f / (1.f + __expf(-(ir + hr)));
    const float zz = 1.f / (1.f + __expf(-(iz + hz)));
    const float n  = tanhf(in_ + r * hn);
    out[row * 768 + c] = (1.f - zz) * n + zz * h[row * 768 + c];
  }
}

__global__ __launch_bounds__(256) void cvt_bf16(
    const float* __restrict__ in, unsigned short* __restrict__ out, int n4)
{
  const int i = blockIdx.x * 256 + threadIdx.x;
  if (i >= n4) return;
  const float4 v = ((const float4*)in)[i];
  us4 o;
  o.x = f2bf(v.x); o.y = f2bf(v.y); o.z = f2bf(v.z); o.w = f2bf(v.w);
  ((us4*)out)[i] = o;
}

__global__ __launch_bounds__(256) void bcast_slots(
    const float* __restrict__ slots, float* __restrict__ mem)
{
  const int i = blockIdx.x * 256 + threadIdx.x;  // 1,572,864 float4s
  ((float4*)mem)[i] = ((const float4*)slots)[i % 24576];
}

// Batched bf16 transpose: in [R,C] -> out [C,R], batch stride R*C both sides.
__global__ void transpose_bf16(const unsigned short* __restrict__ in,
                               unsigned short* __restrict__ out, int R, int C)
{
  __shared__ unsigned short t[32][33];
  const size_t bofs = (size_t)blockIdx.z * R * C;
  const int c0 = blockIdx.x * 32, r0 = blockIdx.y * 32;
  const int x = threadIdx.x, y = threadIdx.y;
#pragma unroll
  for (int k = 0; k < 32; k += 8)
    t[y + k][x] = in[bofs + (size_t)(r0 + y + k) * C + c0 + x];
  __syncthreads();
#pragma unroll
  for (int k = 0; k < 32; k += 8)
    out[bofs + (size_t)(c0 + y + k) * R + r0 + x] = t[x][y + k];
}

// Diagnostic: d_out[0] = ws_size, rest 0 (reported absmax ~= ws_size).
__global__ __launch_bounds__(256) void diag_ws(float* __restrict__ out, float wsz, int n) {
  const int i = blockIdx.x * 256 + threadIdx.x;
  if (i < n) out[i] = (i == 0) ? wsz : 0.f;
}

extern "C" void kernel_launch(void* const* d_in, const int* in_sizes, int n_in,
                              void* d_out, int out_size, void* d_ws, size_t ws_size,
                              hipStream_t stream)
{
  const float* z     = (const float*)d_in[0];
  const float* slots = (const float*)d_in[1];
  const float* ln_g  = (const float*)d_in[2];
  const float* ln_b  = (const float*)d_in[3];
  const float* w_wq = (const float*)d_in[4];  const float* w_bq = (const float*)d_in[5];
  const float* w_wk = (const float*)d_in[6];  const float* w_bk = (const float*)d_in[7];
  const float* w_wv = (const float*)d_in[8];  const float* w_bv = (const float*)d_in[9];
  const float* w_wo = (const float*)d_in[10]; const float* w_bo = (const float*)d_in[11];
  const float* r_wq = (const float*)d_in[12]; const float* r_bq = (const float*)d_in[13];
  const float* r_wk = (const float*)d_in[14]; const float* r_bk = (const float*)d_in[15];
  const float* r_wv = (const float*)d_in[16]; const float* r_bv = (const float*)d_in[17];
  const float* r_wo = (const float*)d_in[18]; const float* r_bo = (const float*)d_in[19];
  const float* g_wih = (const float*)d_in[20]; const float* g_bih = (const float*)d_in[21];
  const float* g_whh = (const float*)d_in[22]; const float* g_bhh = (const float*)d_in[23];

  // ---- static arena (bytes) ----
  constexpr size_t O_R1 = 0;                      // 48MB: Kw | (end) zb2 -> OBr
  constexpr size_t O_R2 = 50331648;               // 48MB: VwT | (end) Kr/VrT/Vrtmp/Abuf_r
  constexpr size_t O_R3 = 100663296;              // 24MB: memf (fp32 state)
  constexpr size_t O_R4 = 125829120;              // 48MB: zb | memln+memb | (end) Qr
  constexpr size_t O_R6 = 176160768;              // 32MB: phase scratch
  constexpr size_t O_W  = 209715200;              // 15.75MB: bf16 weights
  constexpr size_t NEED = 226230272;

  if (ws_size < NEED) {
    const int n = out_size;
    hipLaunchKernelGGL(diag_ws, dim3((n + 255) / 256), dim3(256), 0, stream,
                       (float*)d_out, (float)ws_size, n);
    return;
  }

  char* ws = (char*)d_ws;
  unsigned short* Kw    = (unsigned short*)(ws + O_R1);
  unsigned short* zb2   = (unsigned short*)(ws + O_R1);            // end phase
  unsigned short* OBr   = (unsigned short*)(ws + O_R1);            // end phase (after zb2 dead)
  unsigned short* VwT   = (unsigned short*)(ws + O_R2);
  unsigned short* Kr    = (unsigned short*)(ws + O_R2);
  unsigned short* VrT   = (unsigned short*)(ws + O_R2 + 12582912);
  unsigned short* Vrtmp = (unsigned short*)(ws + O_R2 + 25165824);
  unsigned short* Abr   = (unsigned short*)(ws + O_R2 + 37748736); // read-attn A bf16
  float*          memf  = (float*)(ws + O_R3);
  unsigned short* zb    = (unsigned short*)(ws + O_R4);            // prologue
  float*          memln = (float*)(ws + O_R4);                     // loop
  unsigned short* memb  = (unsigned short*)(ws + O_R4 + 25165824); // loop
  unsigned short* Qr    = (unsigned short*)(ws + O_R4);            // end phase
  unsigned short* tmpV  = (unsigned short*)(ws + O_R6);            // prologue chunk
  unsigned short* Qs    = (unsigned short*)(ws + O_R6);            // loop
  float*          Sbuf  = (float*)(ws + O_R6 + 12582912);
  unsigned short* Abuf  = (unsigned short*)(ws + O_R6);
  unsigned short* OB    = (unsigned short*)(ws + O_R6 + 8388608);
  unsigned short* updb  = (unsigned short*)(ws + O_R6 + 20971520);
  float*          gic   = (float*)(ws + O_R6);
  float*          ghc   = (float*)(ws + O_R6 + 9437184);
  unsigned short* memb2 = (unsigned short*)(ws + O_R6);            // end phase
  float*          Sbr   = (float*)(ws + O_R6 + 12582912);          // end phase
  unsigned short* wqb  = (unsigned short*)(ws + O_W);
  unsigned short* wkb  = wqb + 589824;
  unsigned short* wvb  = wkb + 589824;
  unsigned short* wob  = wvb + 589824;
  unsigned short* rqb  = wob + 589824;
  unsigned short* rkb  = rqb + 589824;
  unsigned short* rvb  = rkb + 589824;
  unsigned short* rob  = rvb + 589824;
  unsigned short* wihb = rob + 589824;
  unsigned short* whhb = wihb + 1769472;

  const float scale = 1.0f / sqrtf(768.f);

  auto cvt = [&](const float* src, unsigned short* dst, size_t n) {
    const int n4 = (int)(n / 4);
    hipLaunchKernelGGL(cvt_bf16, dim3((n4 + 255) / 256), dim3(256), 0, stream, src, dst, n4);
  };

  // ---- prologue: converts, memory init, loop-invariant Kw / VwT ----
  cvt(w_wq, wqb, 589824);  cvt(w_wk, wkb, 589824);
  cvt(w_wv, wvb, 589824);  cvt(w_wo, wob, 589824);
  cvt(r_wq, rqb, 589824);  cvt(r_wk, rkb, 589824);
  cvt(r_wv, rvb, 589824);  cvt(r_wo, rob, 589824);
  cvt(g_wih, wihb, 1769472); cvt(g_whh, whhb, 1769472);
  cvt(z, zb, 32768ull * 768);
  hipLaunchKernelGGL(bcast_slots, dim3(6144), dim3(256), 0, stream, slots, memf);

  hipLaunchKernelGGL((gemm_nt<1, true>), dim3(6, 256, 1), dim3(256), 0, stream,
      zb, wkb, w_bk, (void*)Kw, 32768, 768, 768, 0ll, 0ll, 0ll, 1.0f);
  for (int c = 0; c < 4; ++c) {  // Vw in 16-batch chunks -> transpose into VwT
    hipLaunchKernelGGL((gemm_nt<1, true>), dim3(6, 64, 1), dim3(256), 0, stream,
        zb + (size_t)c * 16 * 512 * 768, wvb, w_bv, (void*)tmpV,
        8192, 768, 768, 0ll, 0ll, 0ll, 1.0f);
    hipLaunchKernelGGL(transpose_bf16, dim3(24, 16, 16), dim3(32, 8), 0, stream,
        tmpV, VwT + (size_t)c * 16 * 768 * 512, 512, 768);
  }

  // ---- T=3 recurrence ----
  for (int t = 0; t < 3; ++t) {
    hipLaunchKernelGGL(ln_kernel, dim3(2048), dim3(256), 0, stream,
        memf, memln, memb, ln_g, ln_b);
    hipLaunchKernelGGL((gemm_nt<1, true>), dim3(6, 64, 1), dim3(256), 0, stream,
        memb, wqb, w_bq, (void*)Qs, 8192, 768, 768, 0ll, 0ll, 0ll, 1.0f);
    hipLaunchKernelGGL((gemm_nt<0, false>), dim3(4, 1, 64), dim3(256), 0, stream,
        Qs, Kw, (const float*)nullptr, (void*)Sbuf, 128, 512, 768,
        (long long)(128 * 768), (long long)(512 * 768), (long long)(128 * 512), scale);
    hipLaunchKernelGGL((softmax_kernel<512>), dim3(2048), dim3(256), 0, stream, Sbuf, Abuf);
    hipLaunchKernelGGL((gemm_nt<1, false>), dim3(6, 1, 64), dim3(256), 0, stream,
        Abuf, VwT, (const float*)nullptr, (void*)OB, 128, 768, 512,
        (long long)(128 * 512), (long long)(768 * 512), (long long)(128 * 768), 1.0f);
    hipLaunchKernelGGL((gemm_nt<1, true>), dim3(6, 64, 1), dim3(256), 0, stream,
        OB, wob, w_bo, (void*)updb, 8192, 768, 768, 0ll, 0ll, 0ll, 1.0f);
    for (int c = 0; c < 8; ++c) {  // GRU in 1024-row chunks
      hipLaunchKernelGGL((gemm_nt<0, true>), dim3(18, 8, 1), dim3(256), 0, stream,
          updb + (size_t)c * 1024 * 768, wihb, g_bih, (void*)gic,
          1024, 2304, 768, 0ll, 0ll, 0ll, 1.0f);
      hipLaunchKernelGGL((gemm_nt<0, true>), dim3(18, 8, 1), dim3(256), 0, stream,
          memb + (size_t)c * 1024 * 768, whhb, g_bhh, (void*)ghc,
          1024, 2304, 768, 0ll, 0ll, 0ll, 1.0f);
      hipLaunchKernelGGL(gru_combine, dim3(1024), dim3(256), 0, stream,
          gic, ghc, memln + (size_t)c * 1024 * 768, memf + (size_t)c * 1024 * 768);
    }
  }

  // ---- read attention: out = MHA(q=z, k=memory, v=memory) ----
  cvt(memf, memb2, 8192ull * 768);
  hipLaunchKernelGGL((gemm_nt<1, true>), dim3(6, 64, 1), dim3(256), 0, stream,
      memb2, rkb, r_bk, (void*)Kr, 8192, 768, 768, 0ll, 0ll, 0ll, 1.0f);
  hipLaunchKernelGGL((gemm_nt<1, true>), dim3(6, 64, 1), dim3(256), 0, stream,
      memb2, rvb, r_bv, (void*)Vrtmp, 8192, 768, 768, 0ll, 0ll, 0ll, 1.0f);
  hipLaunchKernelGGL(transpose_bf16, dim3(24, 4, 64), dim3(32, 8), 0, stream,
      Vrtmp, VrT, 128, 768);
  cvt(z, zb2, 32768ull * 768);
  hipLaunchKernelGGL((gemm_nt<1, true>), dim3(6, 256, 1), dim3(256), 0, stream,
      zb2, rqb, r_bq, (void*)Qr, 32768, 768, 768, 0ll, 0ll, 0ll, 1.0f);
  hipLaunchKernelGGL((gemm_nt<0, false>), dim3(1, 4, 64), dim3(256), 0, stream,
      Qr, Kr, (const float*)nullptr, (void*)Sbr, 512, 128, 768,
      (long long)(512 * 768), (long long)(128 * 768), (long long)(512 * 128), scale);
  hipLaunchKernelGGL((softmax_kernel<128>), dim3(8192), dim3(256), 0, stream, Sbr, Abr);
  hipLaunchKernelGGL((gemm_nt<1, false>), dim3(6, 4, 64), dim3(256), 0, stream,
      Abr, VrT, (const float*)nullptr, (void*)OBr, 512, 768, 128,
      (long long)(512 * 128), (long long)(768 * 128), (long long)(512 * 768), 1.0f);
  hipLaunchKernelGGL((gemm_nt<0, true>), dim3(6, 256, 1), dim3(256), 0, stream,
      OBr, rob, r_bo, d_out, 32768, 768, 768, 0ll, 0ll, 0ll, 1.0f);
}

// Round 3
// 1195.106 us; speedup vs baseline: 1.7492x; 1.7492x over previous
//
#include <hip/hip_runtime.h>
#include <hip/hip_bf16.h>
#include <math.h>

// Memory module: E=768, S=128, T=3, B=64, L=512. fp32 in/out.
// bf16 MFMA GEMMs (fp32 accum); LN/softmax/GRU combine in fp32 (gates stored bf16).
// Arena: 213,665,792 B static plan with liveness-based aliasing.

typedef __attribute__((ext_vector_type(4))) float f32x4;
typedef __attribute__((ext_vector_type(8))) short short8;
typedef __attribute__((ext_vector_type(4))) unsigned short us4;

__device__ __forceinline__ unsigned short f2bf(float x) {
  union { float f; unsigned u; } v; v.f = x;
  unsigned r = v.u + 0x7fffu + ((v.u >> 16) & 1u);  // RNE
  return (unsigned short)(r >> 16);
}
__device__ __forceinline__ float bf2f(unsigned short u) {
  union { unsigned u; float f; } v; v.u = (unsigned)u << 16; return v.f;
}

__device__ __forceinline__ void g2l16(const void* g, void* l) {
  __builtin_amdgcn_global_load_lds(
      (const __attribute__((address_space(1))) unsigned int*)g,
      (__attribute__((address_space(3))) unsigned int*)l, 16, 0, 0);
}

__device__ __forceinline__ float wsum(float v) {
#pragma unroll
  for (int o = 32; o > 0; o >>= 1) v += __shfl_xor(v, o, 64);
  return v;
}
__device__ __forceinline__ float wmax(float v) {
#pragma unroll
  for (int o = 32; o > 0; o >>= 1) v = fmaxf(v, __shfl_xor(v, o, 64));
  return v;
}

// C = alpha*(A @ B^T) + bias. A[M,K] bf16 lda=K, B[N,K] bf16 ldb=K, C[M,N] ldc=N.
// Batched over z (element strides sA/sB/sC, bias stride sBias). OMODE 0 fp32, 1 bf16.
// T1: bijective XCD swizzle over the flattened grid (m204).
template<int OMODE, bool BIAS>
__global__ __launch_bounds__(256) void gemm_nt(
    const unsigned short* __restrict__ Ag, const unsigned short* __restrict__ Bg,
    const float* __restrict__ bias, void* __restrict__ Cg,
    int M, int N, int K, long long sA, long long sB, long long sC,
    long long sBias, float alpha)
{
  __shared__ __align__(16) unsigned short As[128 * 32];
  __shared__ __align__(16) unsigned short Bs[128 * 32];

  const int tid  = threadIdx.x;
  const int lane = tid & 63;
  const int wv   = tid >> 6;           // 0..3
  const int wr   = wv >> 1, wc = wv & 1;

  // T1 XCD-aware bijective swizzle (m204)
  const int gx = gridDim.x, gy = gridDim.y, gz = gridDim.z;
  const int nwg = gx * gy * gz;
  const int lin = blockIdx.x + gx * (blockIdx.y + gy * blockIdx.z);
  const int q = nwg >> 3, r = nwg & 7;
  const int xcd = lin & 7, jj = lin >> 3;
  const int w = (xcd < r ? xcd * (q + 1) : r * (q + 1) + (xcd - r) * q) + jj;
  const int tn = w % gx;
  const int t2 = w / gx;
  const int tm = t2 % gy;
  const long long bz = t2 / gy;

  const unsigned short* A = Ag + bz * sA + (size_t)tm * 128 * K;
  const unsigned short* B = Bg + bz * sB + (size_t)tn * 128 * K;

  const int srow = wv * 16 + (lane >> 2);   // staging row (+ i*64)
  const int kby  = (lane & 3) * 16;         // byte offset within 64B k-row

  f32x4 acc[4][4];
#pragma unroll
  for (int a = 0; a < 4; ++a)
#pragma unroll
    for (int b = 0; b < 4; ++b) acc[a][b] = (f32x4)(0.f);

  const int mrow = wr * 64 + (lane & 15);
  const int nrow = wc * 64 + (lane & 15);
  const int koff = (lane >> 4) * 8;

  for (int kt = 0; kt < K; kt += 32) {
#pragma unroll
    for (int i = 0; i < 2; ++i) {
      g2l16((const char*)(A + (size_t)(i * 64 + srow) * K + kt) + kby,
            (char*)As + i * 4096 + wv * 1024);
      g2l16((const char*)(B + (size_t)(i * 64 + srow) * K + kt) + kby,
            (char*)Bs + i * 4096 + wv * 1024);
    }
    __syncthreads();
    short8 af[4], bf[4];
#pragma unroll
    for (int a = 0; a < 4; ++a) af[a] = *(const short8*)&As[(mrow + a * 16) * 32 + koff];
#pragma unroll
    for (int b = 0; b < 4; ++b) bf[b] = *(const short8*)&Bs[(nrow + b * 16) * 32 + koff];
#pragma unroll
    for (int a = 0; a < 4; ++a)
#pragma unroll
      for (int b = 0; b < 4; ++b)
        acc[a][b] = __builtin_amdgcn_mfma_f32_16x16x32_bf16(af[a], bf[b], acc[a][b], 0, 0, 0);
    __syncthreads();
  }

  const size_t cb = (size_t)(bz * sC);
#pragma unroll
  for (int a = 0; a < 4; ++a) {
    const int row0 = tm * 128 + wr * 64 + a * 16 + (lane >> 4) * 4;
#pragma unroll
    for (int b = 0; b < 4; ++b) {
      const int col = tn * 128 + wc * 64 + b * 16 + (lane & 15);
      float bv = 0.f;
      if (BIAS) bv = bias[bz * sBias + col];
#pragma unroll
      for (int rr = 0; rr < 4; ++rr) {
        float v = acc[a][b][rr] * alpha + bv;
        if constexpr (OMODE == 0)
          ((float*)Cg)[cb + (size_t)(row0 + rr) * N + col] = v;
        else
          ((unsigned short*)Cg)[cb + (size_t)(row0 + rr) * N + col] = f2bf(v);
      }
    }
  }
}

// LayerNorm rows of 768 -> bf16 only. One wave per row, 4 rows/block.
__global__ __launch_bounds__(256) void ln_kernel(
    const float* __restrict__ x, unsigned short* __restrict__ yb,
    const float* __restrict__ g, const float* __restrict__ b)
{
  const int row  = blockIdx.x * 4 + (threadIdx.x >> 6);
  const int lane = threadIdx.x & 63;
  const float* xr = x + (size_t)row * 768;
  float v[12];
  float s = 0.f;
#pragma unroll
  for (int j = 0; j < 12; ++j) { v[j] = xr[lane + 64 * j]; s += v[j]; }
  s = wsum(s);
  const float mu = s * (1.f / 768.f);
  float q = 0.f;
#pragma unroll
  for (int j = 0; j < 12; ++j) { const float d = v[j] - mu; q += d * d; }
  q = wsum(q);
  const float rstd = rsqrtf(q * (1.f / 768.f) + 1e-5f);
  unsigned short* ybr = yb + (size_t)row * 768;
#pragma unroll
  for (int j = 0; j < 12; ++j) {
    const int c = lane + 64 * j;
    ybr[c] = f2bf((v[j] - mu) * rstd * g[c] + b[c]);
  }
}

template<int LR>
__global__ __launch_bounds__(256) void softmax_kernel(
    const float* __restrict__ sc, unsigned short* __restrict__ p)
{
  const int row  = blockIdx.x * 4 + (threadIdx.x >> 6);
  const int lane = threadIdx.x & 63;
  constexpr int PER = LR / 64;
  const float* sr = sc + (size_t)row * LR;
  float v[PER];
  float m = -1e30f;
#pragma unroll
  for (int j = 0; j < PER; ++j) { v[j] = sr[lane + 64 * j]; m = fmaxf(m, v[j]); }
  m = wmax(m);
  float s = 0.f;
#pragma unroll
  for (int j = 0; j < PER; ++j) { v[j] = __expf(v[j] - m); s += v[j]; }
  s = wsum(s);
  const float inv = 1.f / s;
  unsigned short* pr = p + (size_t)row * LR;
#pragma unroll
  for (int j = 0; j < PER; ++j) pr[lane + 64 * j] = f2bf(v[j] * inv);
}

// GRU combine with inline LN: h = LN(mem_row); gates gi/gh bf16 [rows,2304] (r,z,n).
// mem updated in place. One block (256 thr) per row.
__global__ __launch_bounds__(256) void gru_ln_combine(
    const unsigned short* __restrict__ gi, const unsigned short* __restrict__ gh,
    float* __restrict__ mem, const float* __restrict__ g, const float* __restrict__ b)
{
  __shared__ float ps[4], pq[4];
  const size_t row = blockIdx.x;
  const int tid = threadIdx.x, wv = tid >> 6, lane = tid & 63;
  float* mr = mem + row * 768;
  float v[3];
  float s = 0.f, q = 0.f;
#pragma unroll
  for (int k = 0; k < 3; ++k) {
    v[k] = mr[tid + 256 * k];
    s += v[k]; q += v[k] * v[k];
  }
  s = wsum(s); q = wsum(q);
  if (lane == 0) { ps[wv] = s; pq[wv] = q; }
  __syncthreads();
  s = ps[0] + ps[1] + ps[2] + ps[3];
  q = pq[0] + pq[1] + pq[2] + pq[3];
  const float mu = s * (1.f / 768.f);
  const float var = q * (1.f / 768.f) - mu * mu;
  const float rstd = rsqrtf(var + 1e-5f);
#pragma unroll
  for (int k = 0; k < 3; ++k) {
    const int c = tid + 256 * k;
    const float h = (v[k] - mu) * rstd * g[c] + b[c];
    const float ir  = bf2f(gi[row * 2304 + c]);
    const float iz  = bf2f(gi[row * 2304 + 768 + c]);
    const float in_ = bf2f(gi[row * 2304 + 1536 + c]);
    const float hr  = bf2f(gh[row * 2304 + c]);
    const float hz  = bf2f(gh[row * 2304 + 768 + c]);
    const float hn  = bf2f(gh[row * 2304 + 1536 + c]);
    const float rg = 1.f / (1.f + __expf(-(ir + hr)));
    const float zg = 1.f / (1.f + __expf(-(iz + hz)));
    const float n  = tanhf(in_ + rg * hn);
    mr[c] = (1.f - zg) * n + zg * h;
  }
}

__global__ __launch_bounds__(256) void cvt_bf16(
    const float* __restrict__ in, unsigned short* __restrict__ out, int n4)
{
  const int i = blockIdx.x * 256 + threadIdx.x;
  if (i >= n4) return;
  const float4 v = ((const float4*)in)[i];
  us4 o;
  o.x = f2bf(v.x); o.y = f2bf(v.y); o.z = f2bf(v.z); o.w = f2bf(v.w);
  ((us4*)out)[i] = o;
}

__global__ __launch_bounds__(256) void bcast_slots(
    const float* __restrict__ slots, float* __restrict__ mem)
{
  const int i = blockIdx.x * 256 + threadIdx.x;  // 1,572,864 float4s
  ((float4*)mem)[i] = ((const float4*)slots)[i % 24576];
}

// Batched bf16 transpose: in [R,C] -> out [C,R], batch stride R*C both sides.
__global__ void transpose_bf16(const unsigned short* __restrict__ in,
                               unsigned short* __restrict__ out, int R, int C)
{
  __shared__ unsigned short t[32][33];
  const size_t bofs = (size_t)blockIdx.z * R * C;
  const int c0 = blockIdx.x * 32, r0 = blockIdx.y * 32;
  const int x = threadIdx.x, y = threadIdx.y;
#pragma unroll
  for (int k = 0; k < 32; k += 8)
    t[y + k][x] = in[bofs + (size_t)(r0 + y + k) * C + c0 + x];
  __syncthreads();
#pragma unroll
  for (int k = 0; k < 32; k += 8)
    out[bofs + (size_t)(c0 + y + k) * R + r0 + x] = t[x][y + k];
}

__global__ __launch_bounds__(256) void diag_ws(float* __restrict__ out, float wsz, int n) {
  const int i = blockIdx.x * 256 + threadIdx.x;
  if (i < n) out[i] = (i == 0) ? wsz : 0.f;
}

extern "C" void kernel_launch(void* const* d_in, const int* in_sizes, int n_in,
                              void* d_out, int out_size, void* d_ws, size_t ws_size,
                              hipStream_t stream)
{
  const float* z     = (const float*)d_in[0];
  const float* slots = (const float*)d_in[1];
  const float* ln_g  = (const float*)d_in[2];
  const float* ln_b  = (const float*)d_in[3];
  const float* w_wq = (const float*)d_in[4];  const float* w_bq = (const float*)d_in[5];
  const float* w_wk = (const float*)d_in[6];  const float* w_bk = (const float*)d_in[7];
  const float* w_wv = (const float*)d_in[8];  const float* w_bv = (const float*)d_in[9];
  const float* w_wo = (const float*)d_in[10]; const float* w_bo = (const float*)d_in[11];
  const float* r_wq = (const float*)d_in[12]; const float* r_bq = (const float*)d_in[13];
  const float* r_wk = (const float*)d_in[14]; const float* r_bk = (const float*)d_in[15];
  const float* r_wv = (const float*)d_in[16]; const float* r_bv = (const float*)d_in[17];
  const float* r_wo = (const float*)d_in[18]; const float* r_bo = (const float*)d_in[19];
  const float* g_wih = (const float*)d_in[20]; const float* g_bih = (const float*)d_in[21];
  const float* g_whh = (const float*)d_in[22]; const float* g_bhh = (const float*)d_in[23];

  // ---- arena (bytes) ----
  constexpr size_t O_W    = 0;            // 16,533,504: bf16 weights + bias pair
  constexpr size_t O_memf = 16533504;     // 24MB fp32 memory state
  constexpr size_t O_Kw   = 41699328;     // 48MB: Kw | end: zb2 -> OBr
  constexpr size_t O_VwT  = 92030976;     // 48MB: VwT | end: Qr
  constexpr size_t O_L    = 142362624;    // 68MB phase scratch
  constexpr size_t NEED   = 213665792;

  if (ws_size < NEED) {
    hipLaunchKernelGGL(diag_ws, dim3((out_size + 255) / 256), dim3(256), 0, stream,
                       (float*)d_out, (float)ws_size, out_size);
    return;
  }

  char* ws = (char*)d_ws;
  // weights
  unsigned short* wqb  = (unsigned short*)(ws + O_W);
  unsigned short* wkb  = wqb + 589824;
  unsigned short* wvb  = wkb + 589824;
  unsigned short* wob  = wvb + 589824;
  unsigned short* rqb  = wob + 589824;
  unsigned short* rkb  = rqb + 589824;
  unsigned short* rvb  = rkb + 589824;
  unsigned short* rob  = rvb + 589824;
  unsigned short* wihb = rob + 589824;    // 2304x768
  unsigned short* whhb = wihb + 1769472;  // 2304x768
  float* bih_c = (float*)(ws + O_W + 16515072);  // 2304 f32
  float* bhh_c = bih_c + 2304;
  // persistent
  float* memf = (float*)(ws + O_memf);
  unsigned short* Kw  = (unsigned short*)(ws + O_Kw);
  unsigned short* zb2 = (unsigned short*)(ws + O_Kw);
  unsigned short* OBr = (unsigned short*)(ws + O_Kw);
  unsigned short* VwT = (unsigned short*)(ws + O_VwT);
  unsigned short* Qr  = (unsigned short*)(ws + O_VwT);
  // L region
  char* L = ws + O_L;
  unsigned short* zb    = (unsigned short*)(L + 0);          // prologue (48MB)
  unsigned short* tmpV  = (unsigned short*)(L + 50331648);   // prologue (12.6MB)
  unsigned short* memb  = (unsigned short*)(L + 0);          // loop
  unsigned short* Qs    = (unsigned short*)(L + 12582912);
  float*          Sbuf  = (float*)(L + 25165824);            // 16MB
  unsigned short* Abuf  = (unsigned short*)(L + 41943040);   // 8MB
  unsigned short* OB    = (unsigned short*)(L + 25165824);   // alias Sbuf (dead)
  unsigned short* updb  = (unsigned short*)(L + 12582912);   // alias Qs (dead)
  unsigned short* gib   = (unsigned short*)(L + 25165824);   // 18.9MB (OB dead)
  unsigned short* ghb   = (unsigned short*)(L + 44040192);   // 18.9MB
  unsigned short* memb2 = (unsigned short*)(L + 0);          // end
  unsigned short* Kr    = (unsigned short*)(L + 12582912);
  unsigned short* Vrtmp = (unsigned short*)(L + 25165824);
  unsigned short* VrT   = (unsigned short*)(L + 37748736);
  float*          Sbr   = (float*)(L + 50331648);            // 16MB
  unsigned short* Abr   = (unsigned short*)(L + 25165824);   // Vrtmp dead

  const float scale = 1.0f / sqrtf(768.f);

  auto cvt = [&](const float* src, unsigned short* dst, size_t n) {
    const int n4 = (int)(n / 4);
    hipLaunchKernelGGL(cvt_bf16, dim3((n4 + 255) / 256), dim3(256), 0, stream, src, dst, n4);
  };

  // ---- prologue ----
  cvt(w_wq, wqb, 589824);  cvt(w_wk, wkb, 589824);
  cvt(w_wv, wvb, 589824);  cvt(w_wo, wob, 589824);
  cvt(r_wq, rqb, 589824);  cvt(r_wk, rkb, 589824);
  cvt(r_wv, rvb, 589824);  cvt(r_wo, rob, 589824);
  cvt(g_wih, wihb, 1769472); cvt(g_whh, whhb, 1769472);
  hipMemcpyAsync(bih_c, g_bih, 2304 * 4, hipMemcpyDeviceToDevice, stream);
  hipMemcpyAsync(bhh_c, g_bhh, 2304 * 4, hipMemcpyDeviceToDevice, stream);
  cvt(z, zb, 32768ull * 768);
  hipLaunchKernelGGL(bcast_slots, dim3(6144), dim3(256), 0, stream, slots, memf);

  hipLaunchKernelGGL((gemm_nt<1, true>), dim3(6, 256, 1), dim3(256), 0, stream,
      zb, wkb, w_bk, (void*)Kw, 32768, 768, 768, 0ll, 0ll, 0ll, 0ll, 1.0f);
  for (int c = 0; c < 4; ++c) {
    hipLaunchKernelGGL((gemm_nt<1, true>), dim3(6, 64, 1), dim3(256), 0, stream,
        zb + (size_t)c * 16 * 512 * 768, wvb, w_bv, (void*)tmpV,
        8192, 768, 768, 0ll, 0ll, 0ll, 0ll, 1.0f);
    hipLaunchKernelGGL(transpose_bf16, dim3(24, 16, 16), dim3(32, 8), 0, stream,
        tmpV, VwT + (size_t)c * 16 * 768 * 512, 512, 768);
  }

  // batched-gate strides (z=0: gi from updb/Wih/bih; z=1: gh from memb/Whh/bhh)
  const long long sA_g = (long long)(memb - updb);      // negative-safe ll
  const long long sB_g = 1769472ll;
  const long long sC_g = (long long)(ghb - gib);
  const long long sBias_g = 2304ll;

  // ---- T=3 recurrence ----
  for (int t = 0; t < 3; ++t) {
    hipLaunchKernelGGL(ln_kernel, dim3(2048), dim3(256), 0, stream,
        memf, memb, ln_g, ln_b);
    hipLaunchKernelGGL((gemm_nt<1, true>), dim3(6, 64, 1), dim3(256), 0, stream,
        memb, wqb, w_bq, (void*)Qs, 8192, 768, 768, 0ll, 0ll, 0ll, 0ll, 1.0f);
    hipLaunchKernelGGL((gemm_nt<0, false>), dim3(4, 1, 64), dim3(256), 0, stream,
        Qs, Kw, (const float*)nullptr, (void*)Sbuf, 128, 512, 768,
        (long long)(128 * 768), (long long)(512 * 768), (long long)(128 * 512), 0ll, scale);
    hipLaunchKernelGGL((softmax_kernel<512>), dim3(2048), dim3(256), 0, stream, Sbuf, Abuf);
    hipLaunchKernelGGL((gemm_nt<1, false>), dim3(6, 1, 64), dim3(256), 0, stream,
        Abuf, VwT, (const float*)nullptr, (void*)OB, 128, 768, 512,
        (long long)(128 * 512), (long long)(768 * 512), (long long)(128 * 768), 0ll, 1.0f);
    hipLaunchKernelGGL((gemm_nt<1, true>), dim3(6, 64, 1), dim3(256), 0, stream,
        OB, wob, w_bo, (void*)updb, 8192, 768, 768, 0ll, 0ll, 0ll, 0ll, 1.0f);
    for (int c = 0; c < 2; ++c) {  // 4096-row chunks, gi+gh in one batched launch
      hipLaunchKernelGGL((gemm_nt<1, true>), dim3(18, 32, 2), dim3(256), 0, stream,
          updb + (size_t)c * 4096 * 768, wihb, bih_c, (void*)gib,
          4096, 2304, 768, sA_g, sB_g, sC_g, sBias_g, 1.0f);
      hipLaunchKernelGGL(gru_ln_combine, dim3(4096), dim3(256), 0, stream,
          gib, ghb, memf + (size_t)c * 4096 * 768, ln_g, ln_b);
    }
  }

  // ---- read attention: out = MHA(q=z, k=memory, v=memory) ----
  cvt(memf, memb2, 8192ull * 768);
  hipLaunchKernelGGL((gemm_nt<1, true>), dim3(6, 64, 1), dim3(256), 0, stream,
      memb2, rkb, r_bk, (void*)Kr, 8192, 768, 768, 0ll, 0ll, 0ll, 0ll, 1.0f);
  hipLaunchKernelGGL((gemm_nt<1, true>), dim3(6, 64, 1), dim3(256), 0, stream,
      memb2, rvb, r_bv, (void*)Vrtmp, 8192, 768, 768, 0ll, 0ll, 0ll, 0ll, 1.0f);
  hipLaunchKernelGGL(transpose_bf16, dim3(24, 4, 64), dim3(32, 8), 0, stream,
      Vrtmp, VrT, 128, 768);
  cvt(z, zb2, 32768ull * 768);
  hipLaunchKernelGGL((gemm_nt<1, true>), dim3(6, 256, 1), dim3(256), 0, stream,
      zb2, rqb, r_bq, (void*)Qr, 32768, 768, 768, 0ll, 0ll, 0ll, 0ll, 1.0f);
  hipLaunchKernelGGL((gemm_nt<0, false>), dim3(1, 4, 64), dim3(256), 0, stream,
      Qr, Kr, (const float*)nullptr, (void*)Sbr, 512, 128, 768,
      (long long)(512 * 768), (long long)(128 * 768), (long long)(512 * 128), 0ll, scale);
  hipLaunchKernelGGL((softmax_kernel<128>), dim3(8192), dim3(256), 0, stream, Sbr, Abr);
  hipLaunchKernelGGL((gemm_nt<1, false>), dim3(6, 4, 64), dim3(256), 0, stream,
      Abr, VrT, (const float*)nullptr, (void*)OBr, 512, 768, 128,
      (long long)(512 * 128), (long long)(768 * 128), (long long)(512 * 768), 0ll, 1.0f);
  hipLaunchKernelGGL((gemm_nt<0, true>), dim3(6, 256, 1), dim3(256), 0, stream,
      OBr, rob, r_bo, d_out, 32768, 768, 768, 0ll, 0ll, 0ll, 0ll, 1.0f);
}